// Round 26
// baseline (30.512 us; speedup 1.0000x reference)
//
#include <hip/hip_runtime.h>

// ChamferDistance: B=4, N=M=8192, fp32 3-D points.
// R26: R24 (champion, 27.2 µs) + 2 AFRAGS/WAVE (1 LDS read -> 2 MFMA).
// R25 post-mortem: barrier-halving regressed (28.1) — join skew not the
// residual. Corrected floors for R24: MFMA 6.8 µs (524288 MFMA / 256 CU x
// 8 cyc), LDS-read pipe 10.2 µs (256 ds_read_b128/stage/CU x 12 cyc x 8,
// each read feeding ONE MFMA), VALU 4.6 µs. LDS pipe is the biggest floor
// and halvable: wave = row-PAIR (w&3) x col-QUARTER (w>>2), 2 afrags, per
// tile-pair {2 ds_read + 4 MFMA + 32 min3} -> reads/stage 256 -> 128.
// Cross-quarter combine: int-punned LDS atomicMin (ds_min_i32) into a
// 32 KB PINF-initialized csh (clamp >= 0 before pun -> order-preserving),
// then q==0 waves butterfly + direct store. No global atomics, no init
// kernel, no workspace, ONE launch.
// Math verified since R4 (absmax 0.0156): d = n1+n2-2x.y, hi/lo bf16 K=16;
// C layout 32x32: col=lane&31, row=(r&3)+8*(r>>2)+4*(lane>>5).

typedef short  short8 __attribute__((ext_vector_type(8)));
typedef float  f32x16 __attribute__((ext_vector_type(16)));

#define B_       4
#define NPT      8192
#define THREADS  1024
#define NROWBLK  32              // 256 rows per block
#define STAGEPTS 1024            // B points per LDS stage (32 KB packed)
#define NSTAGE   (NPT / STAGEPTS)    // 8
#define PINF_I   0x7f800000

__device__ __forceinline__ unsigned short f2bf(float x) {
    unsigned u = __float_as_uint(x);
    u += 0x7fff + ((u >> 16) & 1);
    return (unsigned short)(u >> 16);
}
__device__ __forceinline__ float bf2f(unsigned short b) {
    return __uint_as_float(((unsigned)b) << 16);
}
#define PK2(a, b) ((((unsigned)(b)) << 16) | (unsigned)(a))

// Pack one row-point into the lane's A-fragment half (kg = lane>>5).
__device__ __forceinline__ short8 packA(const float* __restrict__ p, int kg) {
    const unsigned short one = 0x3f80;
    float x0 = p[0], x1 = p[1], x2 = p[2];
    unsigned short h0 = f2bf(x0), h1 = f2bf(x1), h2 = f2bf(x2);
    unsigned short l0 = f2bf(x0 - bf2f(h0)), l1 = f2bf(x1 - bf2f(h1)), l2 = f2bf(x2 - bf2f(h2));
    unsigned short m0 = f2bf(-2.f * bf2f(h0)), m1 = f2bf(-2.f * bf2f(h1)), m2 = f2bf(-2.f * bf2f(h2));
    unsigned short q0 = f2bf(-2.f * bf2f(l0)), q1 = f2bf(-2.f * bf2f(l1)), q2 = f2bf(-2.f * bf2f(l2));
    float n = x0*x0 + x1*x1 + x2*x2;
    unsigned short nh = f2bf(n), nl = f2bf(n - bf2f(nh));
    short8 r;
    if (kg == 0) {
        r[0] = (short)m0; r[1] = (short)m1; r[2] = (short)m2; r[3] = (short)q0;
        r[4] = (short)q1; r[5] = (short)q2; r[6] = (short)m0; r[7] = (short)m1;
    } else {
        r[0] = (short)m2; r[1] = (short)nh; r[2] = (short)nl; r[3] = (short)one;
        r[4] = (short)one; r[5] = 0; r[6] = 0; r[7] = 0;
    }
    return r;
}

__global__ __launch_bounds__(THREADS, 4)   // 16 waves/block, 1 block/CU, 128-reg cap
void cd_fused(const float* __restrict__ xyz1, const float* __restrict__ xyz2,
              float* __restrict__ out) {
    __shared__ uint4 ysh[STAGEPTS * 2];    // 32 KB: split-K packed B stage

    int bid = blockIdx.x;
    const int rb   = bid & (NROWBLK - 1);  bid >>= 5;
    const int b    = bid & (B_ - 1);       bid >>= 2;
    const int pass = bid;                   // 0: dist1 (rows=cloud1), 1: dist2

    const float* __restrict__ xa = pass ? xyz2 : xyz1;   // row cloud
    const float* __restrict__ xb = pass ? xyz1 : xyz2;   // col cloud
    float* __restrict__ o = out + (size_t)pass * B_ * NPT;

    const int tid  = threadIdx.x;
    const int lane = tid & 63;
    const int w    = tid >> 6;             // 0..15
    const int rp   = w & 3;                // row-pair (64 rows = 2 row-tiles)
    const int q    = w >> 2;               // column quarter (0..3)
    const int l31  = lane & 31;
    const int kg   = lane >> 5;
    const unsigned short one = 0x3f80;

    const size_t bbase  = (size_t)b * NPT;
    const int    myRow0 = rb * 256 + rp * 64;

    // In-register A fragments: 2 row-tiles per wave.
    short8 afrag0 = packA(xa + (bbase + myRow0 +      l31) * 3, kg);
    short8 afrag1 = packA(xa + (bbase + myRow0 + 32 + l31) * 3, kg);

    f32x16 rmin0, rmin1;
    #pragma unroll
    for (int r = 0; r < 16; ++r) {
        rmin0[r] = __int_as_float(PINF_I);
        rmin1[r] = __int_as_float(PINF_I);
    }

    const unsigned short* bsh = (const unsigned short*)ysh;

    for (int s = 0; s < NSTAGE; ++s) {
        // Pack 1024 B points into LDS (one per thread), split-K layout.
        {
            const int p = tid;
            const float* yp = xb + (bbase + (size_t)s * STAGEPTS + p) * 3;
            float y0 = yp[0], y1 = yp[1], y2 = yp[2];
            unsigned short h0 = f2bf(y0), h1 = f2bf(y1), h2 = f2bf(y2);
            unsigned short l0 = f2bf(y0 - bf2f(h0));
            unsigned short l1 = f2bf(y1 - bf2f(h1));
            unsigned short l2 = f2bf(y2 - bf2f(h2));
            float n = y0*y0 + y1*y1 + y2*y2;
            unsigned short nh = f2bf(n), nl = f2bf(n - bf2f(nh));
            const int g = p >> 5, sl = p & 31;
            ysh[g * 64 + sl]      = make_uint4(PK2(h0, h1), PK2(h2, h0), PK2(h1, h2), PK2(l0, l1));
            ysh[g * 64 + 32 + sl] = make_uint4(PK2(l2, one), PK2(one, nh), PK2(nl, 0), PK2(0, 0));
        }
        __syncthreads();

        // This wave's column quarter: 8 tiles = 4 pairs.
        // Per pair: 2 ds_read -> 4 MFMA (2 afrags) -> 32 min3.
        #pragma unroll
        for (int pr = 0; pr < 4; ++pr) {
            const int t0 = q * 8 + pr * 2;
            short8 bf0 = *(const short8*)(bsh + (size_t)t0 * 512 + kg * 256 + l31 * 8);
            short8 bf1 = *(const short8*)(bsh + (size_t)(t0 + 1) * 512 + kg * 256 + l31 * 8);
            f32x16 z = {0.f};
            f32x16 accX = __builtin_amdgcn_mfma_f32_32x32x16_bf16(afrag0, bf0, z, 0, 0, 0);
            f32x16 accY = __builtin_amdgcn_mfma_f32_32x32x16_bf16(afrag0, bf1, z, 0, 0, 0);
            #pragma unroll
            for (int r = 0; r < 16; ++r)
                rmin0[r] = fminf(fminf(accX[r], accY[r]), rmin0[r]);   // v_min3_f32
            accX = __builtin_amdgcn_mfma_f32_32x32x16_bf16(afrag1, bf0, z, 0, 0, 0);
            accY = __builtin_amdgcn_mfma_f32_32x32x16_bf16(afrag1, bf1, z, 0, 0, 0);
            #pragma unroll
            for (int r = 0; r < 16; ++r)
                rmin1[r] = fminf(fminf(accX[r], accY[r]), rmin1[r]);
        }
        __syncthreads();
    }

    // Cross-quarter combine: int-punned LDS atomicMin into 32 KB csh.
    int* csh = (int*)ysh;                  // 8 rowtiles * 16 r * 64 lanes ints
    #pragma unroll
    for (int j = 0; j < 8; ++j) csh[tid * 8 + j] = PINF_I;
    __syncthreads();
    #pragma unroll
    for (int r = 0; r < 16; ++r) {
        const int base = r * 64 + lane;
        atomicMin(&csh[(rp * 2 + 0) * 1024 + base],
                  __float_as_int(fmaxf(rmin0[r], 0.f)));
        atomicMin(&csh[(rp * 2 + 1) * 1024 + base],
                  __float_as_int(fmaxf(rmin1[r], 0.f)));
    }
    __syncthreads();

    // q==0 waves: butterfly each combined row-min across 32 col-slots, store.
    if (q == 0) {
        #pragma unroll
        for (int at = 0; at < 2; ++at) {
            #pragma unroll
            for (int r = 0; r < 16; ++r) {
                float v = __int_as_float(csh[(rp * 2 + at) * 1024 + r * 64 + lane]);
                v = fminf(v, __shfl_xor(v, 1, 64));
                v = fminf(v, __shfl_xor(v, 2, 64));
                v = fminf(v, __shfl_xor(v, 4, 64));
                v = fminf(v, __shfl_xor(v, 8, 64));
                v = fminf(v, __shfl_xor(v, 16, 64));
                if (l31 == 0) {
                    int row = myRow0 + at * 32 + (r & 3) + 8 * (r >> 2) + 4 * kg;
                    o[bbase + row] = v;   // already clamped >= 0
                }
            }
        }
    }
}

extern "C" void kernel_launch(void* const* d_in, const int* in_sizes, int n_in,
                              void* d_out, int out_size, void* d_ws, size_t ws_size,
                              hipStream_t stream) {
    const float* xyz1 = (const float*)d_in[0];
    const float* xyz2 = (const float*)d_in[1];
    // ONE launch, no workspace, no init, no atomics (global).
    cd_fused<<<2 * B_ * NROWBLK, THREADS, 0, stream>>>(xyz1, xyz2, (float*)d_out);
}

// Round 27
// 25.387 us; speedup vs baseline: 1.2019x; 1.2019x over previous
//
#include <hip/hip_runtime.h>

// ChamferDistance: B=4, N=M=8192, fp32 3-D points.
// R27: R24 (champion, 27.2 µs) with FP16 K=7 FORMAT (no hi/lo cross terms).
// R26 post-mortem: 2-afrag quarter-split regressed (30.5) — schedule attacks
// on the LDS floor exhausted. Format attack instead: fp16 (11-bit mantissa)
// makes -2x.y accurate to |x||y|*2^-9 ~ 0.02-0.055 worst-case tails, inside
// the 6.75e-2 threshold WITHOUT compensation -> point payload K=13 -> K=7,
// 32 B -> 16 B:  A=[-2x(3), n1h, n1l, 1, 1, 0]  B=[y(3), 1, 1, n2h, n2l, 0]
// (norms hi/lo fp16 from exact fp32 n, error ~2^-22*n). MFMA k8-15 killed by
// ZERO A-fragments in kg=1 lanes -> B upper half is don't-care; all lanes
// read the same 16 B per point (kg-pairs = 2-way broadcast, free per m136).
// LDS stage 32->16 KB, ds_read bytes HALVED (10.2 -> ~5 µs floor), pack ÷3.
// Geometry byte-for-byte R24: 1024 thr, 256 rows/block, wave = rt(w&7) x
// col-half(w>>3), min3 pairing, 8 stages x 2 barriers, direct store, ONE
// launch, no workspace/init/atomics.
// C layout 32x32 (dtype-independent): col=lane&31, row=(r&3)+8*(r>>2)+4*kg.

typedef _Float16 half8 __attribute__((ext_vector_type(8)));
typedef float    f32x16 __attribute__((ext_vector_type(16)));

#define B_       4
#define NPT      8192
#define THREADS  1024
#define NROWBLK  32              // 256 rows per block
#define STAGEPTS 1024            // B points per LDS stage (16 KB packed)
#define NSTAGE   (NPT / STAGEPTS)    // 8
#define PINF_I   0x7f800000

__device__ __forceinline__ unsigned pkh(_Float16 a, _Float16 b) {
    union { _Float16 h; unsigned short u; } ua, ub;
    ua.h = a; ub.h = b;
    return (((unsigned)ub.u) << 16) | ua.u;
}

// Pack one row-point into the lane's A-fragment (kg=1 lanes: zeros -> kills
// the k8-15 half of the MFMA regardless of B's upper-half contents).
__device__ __forceinline__ half8 packA(const float* __restrict__ p, int kg) {
    half8 r = {};
    if (kg == 0) {
        float x0 = p[0], x1 = p[1], x2 = p[2];
        float n = x0*x0 + x1*x1 + x2*x2;
        _Float16 nh = (_Float16)n;
        _Float16 nl = (_Float16)(n - (float)nh);
        r[0] = (_Float16)(-2.f * x0);
        r[1] = (_Float16)(-2.f * x1);
        r[2] = (_Float16)(-2.f * x2);
        r[3] = nh; r[4] = nl;
        r[5] = (_Float16)1.f; r[6] = (_Float16)1.f;
        r[7] = (_Float16)0.f;
    }
    return r;
}

__global__ __launch_bounds__(THREADS, 4)   // 16 waves/block, 1 block/CU
void cd_fused(const float* __restrict__ xyz1, const float* __restrict__ xyz2,
              float* __restrict__ out) {
    __shared__ uint4 ysh[2048];            // 32 KB (stage uses 16 KB; csh 32 KB)

    int bid = blockIdx.x;
    const int rb   = bid & (NROWBLK - 1);  bid >>= 5;
    const int b    = bid & (B_ - 1);       bid >>= 2;
    const int pass = bid;                   // 0: dist1 (rows=cloud1), 1: dist2

    const float* __restrict__ xa = pass ? xyz2 : xyz1;   // row cloud
    const float* __restrict__ xb = pass ? xyz1 : xyz2;   // col cloud
    float* __restrict__ o = out + (size_t)pass * B_ * NPT;

    const int tid  = threadIdx.x;
    const int lane = tid & 63;
    const int w    = tid >> 6;             // 0..15
    const int rt   = w & 7;                // row-tile within block (8)
    const int h    = w >> 3;               // column half (0 or 1)
    const int l31  = lane & 31;
    const int kg   = lane >> 5;

    const size_t bbase = (size_t)b * NPT;
    const int    myRow = rb * 256 + rt * 32;

    // In-register A fragment (fp16, kg=1 -> zeros).
    half8 afrag = packA(xa + (bbase + myRow + l31) * 3, kg);

    f32x16 rmin;
    #pragma unroll
    for (int r = 0; r < 16; ++r) rmin[r] = __int_as_float(PINF_I);

    const half8* bsh = (const half8*)ysh;

    for (int s = 0; s < NSTAGE; ++s) {
        // Pack 1024 B points into LDS (ONE per thread), 16 B per point:
        // [y0, y1, y2, 1, 1, n2h, n2l, 0] as fp16.
        {
            const int p = tid;
            const float* yp = xb + (bbase + (size_t)s * STAGEPTS + p) * 3;
            float y0 = yp[0], y1 = yp[1], y2 = yp[2];
            float n = y0*y0 + y1*y1 + y2*y2;
            _Float16 nh = (_Float16)n;
            _Float16 nl = (_Float16)(n - (float)nh);
            const _Float16 one = (_Float16)1.f;
            ysh[p] = make_uint4(
                pkh((_Float16)y0, (_Float16)y1),
                pkh((_Float16)y2, one),
                pkh(one, nh),
                pkh(nl, (_Float16)0.f));
        }
        __syncthreads();

        // This wave's column half: 16 tiles = 8 min3 pairs.
        // All 64 lanes read point (t*32 + l31): kg-pairs share the address
        // (2-way broadcast, free); kg=1 operand content is don't-care.
        #pragma unroll
        for (int pr = 0; pr < 8; ++pr) {
            const int t0 = h * 16 + pr * 2;
            half8 bf0 = bsh[t0 * 32 + l31];
            half8 bf1 = bsh[(t0 + 1) * 32 + l31];
            f32x16 z = {0.f};
            f32x16 accX = __builtin_amdgcn_mfma_f32_32x32x16_f16(afrag, bf0, z, 0, 0, 0);
            f32x16 accY = __builtin_amdgcn_mfma_f32_32x32x16_f16(afrag, bf1, z, 0, 0, 0);
            #pragma unroll
            for (int r = 0; r < 16; ++r)
                rmin[r] = fminf(fminf(accX[r], accY[r]), rmin[r]);   // v_min3_f32
        }
        __syncthreads();
    }

    // Cross-half combine via LDS (reuse ysh; [rt][r][lane] = conflict-free).
    float* csh = (float*)ysh;              // 8 * 16 * 64 floats = 32 KB
    if (h == 1) {
        #pragma unroll
        for (int r = 0; r < 16; ++r)
            csh[rt * 1024 + r * 64 + lane] = rmin[r];
    }
    __syncthreads();
    if (h == 0) {
        #pragma unroll
        for (int r = 0; r < 16; ++r) {
            float v = fminf(rmin[r], csh[rt * 1024 + r * 64 + lane]);
            v = fminf(v, __shfl_xor(v, 1, 64));
            v = fminf(v, __shfl_xor(v, 2, 64));
            v = fminf(v, __shfl_xor(v, 4, 64));
            v = fminf(v, __shfl_xor(v, 8, 64));
            v = fminf(v, __shfl_xor(v, 16, 64));
            if (l31 == 0) {
                int row = myRow + (r & 3) + 8 * (r >> 2) + 4 * kg;
                o[bbase + row] = fmaxf(v, 0.f);
            }
        }
    }
}

extern "C" void kernel_launch(void* const* d_in, const int* in_sizes, int n_in,
                              void* d_out, int out_size, void* d_ws, size_t ws_size,
                              hipStream_t stream) {
    const float* xyz1 = (const float*)d_in[0];
    const float* xyz2 = (const float*)d_in[1];
    // ONE launch, no workspace, no init, no atomics.
    cd_fused<<<2 * B_ * NROWBLK, THREADS, 0, stream>>>(xyz1, xyz2, (float*)d_out);
}